// Round 3
// baseline (550.529 us; speedup 1.0000x reference)
//
#include <hip/hip_runtime.h>

#define D 128
#define KNBR 32
#define BATCH 8192
#define NCLASS 60
#define NB 16      // b rows per block
#define NP 32      // (b, side) pairs per block

// ---------------------------------------------------------------------------
// K0: prep. blk0: wqa = Wq@a[:D], wka = Wk@a[D:]
//          blk1: be = We_b @ Wuc[384:512]
//          blks 2..49: Wcomb2 = [Wk@Wuc[128:256]; Wk@Wuc[256:384]; We_w@Wuc[384:512]]
__global__ __launch_bounds__(256) void k_prep(
    const float* __restrict__ Wq, const float* __restrict__ Wk,
    const float* __restrict__ a, const float* __restrict__ Wew,
    const float* __restrict__ Web, const float* __restrict__ Wuc,
    float* __restrict__ wqa, float* __restrict__ wka,
    float* __restrict__ be, float* __restrict__ Wcomb2)
{
    __shared__ float sB[128][129];
    int blk = blockIdx.x, tid = threadIdx.x;
    if (blk == 0) {
        for (int t = tid; t < 128 * 128; t += 256) sB[t >> 7][t & 127] = Wq[t];
        __syncthreads();
        if (tid < 128) {
            float s = 0.f;
            for (int j = 0; j < D; ++j) s += sB[tid][j] * a[j];
            wqa[tid] = s;
        }
        __syncthreads();
        for (int t = tid; t < 128 * 128; t += 256) sB[t >> 7][t & 127] = Wk[t];
        __syncthreads();
        if (tid < 128) {
            float s = 0.f;
            for (int j = 0; j < D; ++j) s += sB[tid][j] * a[D + j];
            wka[tid] = s;
        }
    } else if (blk == 1) {
        if (tid < 128) {
            float acc = 0.f;
            for (int j = 0; j < D; ++j) acc += Web[j] * Wuc[(size_t)(384 + j) * D + tid];
            be[tid] = acc;
        }
    } else {
        int g  = (blk - 2) >> 4;
        int rb = ((blk - 2) & 15) * 8;
        const float* A = (g == 2) ? Wew : Wk;
        const float* B = Wuc + (size_t)(128 + g * 128) * D;
        for (int t = tid; t < 128 * 128; t += 256) sB[t >> 7][t & 127] = B[t];
        __syncthreads();
        int j = tid & 127, half = tid >> 7;
        float acc[4] = {0.f, 0.f, 0.f, 0.f};
        int r0 = rb + half * 4;
        for (int t = 0; t < 128; ++t) {
            float bv = sB[t][j];
            #pragma unroll
            for (int m = 0; m < 4; ++m)
                acc[m] = fmaf(A[(size_t)(r0 + m) * D + t], bv, acc[m]);
        }
        #pragma unroll
        for (int m = 0; m < 4; ++m)
            Wcomb2[(size_t)(g * 128 + r0 + m) * D + j] = acc[m];
    }
}

// ---------------------------------------------------------------------------
// K1: fully fused per-row pipeline. Each block: 16 b's x 2 sides.
// Phase A: attention -> s_self, s_nbsum (LDS). Phase B: msg GEMM [32x512]@[512x128].
// Phase C: cls GEMM1 [32x128]@[128x128] -> relu -> GEMM2 [32x128]@[128x60] -> out.
__global__ __launch_bounds__(256, 2) void k_fused(
    const float* __restrict__ mem, const float* __restrict__ edge_feat,
    const float* __restrict__ Wuc, const float* __restrict__ Wcomb2,
    const float* __restrict__ be,
    const float* __restrict__ wqa, const float* __restrict__ wka,
    const float* __restrict__ Wc1, const float* __restrict__ Wc2,
    const int* __restrict__ src_idxs, const int* __restrict__ dst_idxs,
    const int* __restrict__ edge_idxs,
    const int* __restrict__ src_nb, const int* __restrict__ dst_nb,
    float* __restrict__ out)
{
    __shared__ __align__(16) float s_self[NP * 132];
    __shared__ __align__(16) float s_nbsum[NP * 132];
    __shared__ __align__(16) float Ast[32 * 33];
    __shared__ __align__(16) float Ws[32 * 128];
    __shared__ __align__(16) float msgT[128 * 35];
    __shared__ int s_eidx[NB];

    int tid = threadIdx.x;
    int b0 = blockIdx.x * NB;
    int lane = tid & 31;
    int grp  = tid >> 5;

    if (tid < NB) s_eidx[tid] = edge_idxs[b0 + tid];

    float4 wq4 = ((const float4*)wqa)[lane];
    float4 wk4 = ((const float4*)wka)[lane];

    // ---------------- Phase A: attention, 8 groups of 32 lanes, 4 iterations
    for (int it = 0; it < 4; ++it) {
        int p = it * 8 + grp;              // pair 0..31
        int side = p >> 4;
        int bb = b0 + (p & 15);
        int self_idx = (side ? dst_idxs : src_idxs)[bb];
        int nb_idx = (side ? dst_nb : src_nb)[(size_t)bb * KNBR + lane];

        // self row: gather + stash + sq = self . wqa
        float4 sv = ((const float4*)(mem + (size_t)self_idx * D))[lane];
        *(float4*)&s_self[p * 132 + lane * 4] = sv;
        float sp = sv.x * wq4.x + sv.y * wq4.y + sv.z * wq4.z + sv.w * wq4.w;
        #pragma unroll
        for (int m = 1; m <= 16; m <<= 1) sp += __shfl_xor(sp, m, 32);
        float sq = sp;

        // pass 1: scores (cooperative gather, butterfly reduce per row)
        float myscore = 0.f;
        #pragma unroll 4
        for (int k = 0; k < KNBR; ++k) {
            int ik = __shfl(nb_idx, k, 32);
            float4 v = ((const float4*)(mem + (size_t)ik * D))[lane];
            float pr = v.x * wk4.x + v.y * wk4.y + v.z * wk4.z + v.w * wk4.w;
            #pragma unroll
            for (int m = 1; m <= 16; m <<= 1) pr += __shfl_xor(pr, m, 32);
            if (k == lane) myscore = pr;
        }
        float x = sq + myscore;
        x = (x >= 0.f) ? x : 0.2f * x;                 // leaky_relu(0.2)
        float mx = x;
        #pragma unroll
        for (int m = 1; m <= 16; m <<= 1) mx = fmaxf(mx, __shfl_xor(mx, m, 32));
        float e = __expf(x - mx);
        float sum = e;
        #pragma unroll
        for (int m = 1; m <= 16; m <<= 1) sum += __shfl_xor(sum, m, 32);
        float attn = e / sum;

        // pass 2: weighted neighbor sum (re-gather, L2-hot)
        float4 acc = make_float4(0.f, 0.f, 0.f, 0.f);
        #pragma unroll 4
        for (int k = 0; k < KNBR; ++k) {
            int ik = __shfl(nb_idx, k, 32);
            float ak = __shfl(attn, k, 32);
            float4 v = ((const float4*)(mem + (size_t)ik * D))[lane];
            acc.x = fmaf(ak, v.x, acc.x);
            acc.y = fmaf(ak, v.y, acc.y);
            acc.z = fmaf(ak, v.z, acc.z);
            acc.w = fmaf(ak, v.w, acc.w);
        }
        *(float4*)&s_nbsum[p * 132 + lane * 4] = acc;
    }
    __syncthreads();

    // ---------------- Phase B: msg = relu(A @ [Wuc; Wcomb2] + be), A = [32 x 512]
    int tr = tid >> 4, tc = tid & 15;          // 16x16 micro grid, 2x8 per thread
    int lc = tid & 31, lr = tid >> 5;          // A staging lanes
    int wc = tid & 127, wk2 = tid >> 7;        // W staging lanes
    float accB[2][8];
    #pragma unroll
    for (int i = 0; i < 2; ++i)
        #pragma unroll
        for (int j = 0; j < 8; ++j) accB[i][j] = 0.f;

    for (int kt = 0; kt < 16; ++kt) {
        int seg = kt >> 2, off = (kt & 3) * 32;
        #pragma unroll
        for (int q = 0; q < 4; ++q) {
            int r = lr + 8 * q;
            float v;
            if (seg == 0)      v = s_self[r * 132 + off + lc];
            else if (seg == 1) v = s_nbsum[r * 132 + off + lc];
            else if (seg == 2) v = s_nbsum[(r ^ 16) * 132 + off + lc];
            else               v = edge_feat[(size_t)s_eidx[r & 15] * D + off + lc];
            Ast[lc * 33 + r] = v;
        }
        int krow0 = kt * 32;
        #pragma unroll
        for (int pp = 0; pp < 16; ++pp) {
            int kk = wk2 + 2 * pp;
            int gr = krow0 + kk;
            Ws[kk * 128 + wc] = (gr < 128) ? Wuc[(size_t)gr * D + wc]
                                           : Wcomb2[(size_t)(gr - 128) * D + wc];
        }
        __syncthreads();
        #pragma unroll 8
        for (int kk = 0; kk < 32; ++kk) {
            float a0 = Ast[kk * 33 + tr * 2];
            float a1 = Ast[kk * 33 + tr * 2 + 1];
            float4 w0 = *(const float4*)&Ws[kk * 128 + tc * 4];
            float4 w1 = *(const float4*)&Ws[kk * 128 + 64 + tc * 4];
            float wr[8] = {w0.x, w0.y, w0.z, w0.w, w1.x, w1.y, w1.z, w1.w};
            #pragma unroll
            for (int j = 0; j < 8; ++j) {
                accB[0][j] = fmaf(a0, wr[j], accB[0][j]);
                accB[1][j] = fmaf(a1, wr[j], accB[1][j]);
            }
        }
        __syncthreads();
    }
    // bias + relu -> msgT[col][row]
    {
        float4 bv0 = *(const float4*)&be[tc * 4];
        float4 bv1 = *(const float4*)&be[64 + tc * 4];
        float b8[8] = {bv0.x, bv0.y, bv0.z, bv0.w, bv1.x, bv1.y, bv1.z, bv1.w};
        #pragma unroll
        for (int i = 0; i < 2; ++i) {
            int r = tr * 2 + i;
            #pragma unroll
            for (int j = 0; j < 4; ++j) {
                msgT[(tc * 4 + j) * 35 + r]        = fmaxf(accB[i][j] + b8[j], 0.f);
                msgT[(64 + tc * 4 + j) * 35 + r]   = fmaxf(accB[i][j + 4] + b8[j + 4], 0.f);
            }
        }
    }
    __syncthreads();

    // ---------------- Phase C: GEMM1 h1 = relu(msg @ Wc1)
    float accC[2][8];
    #pragma unroll
    for (int i = 0; i < 2; ++i)
        #pragma unroll
        for (int j = 0; j < 8; ++j) accC[i][j] = 0.f;

    for (int kt = 0; kt < 4; ++kt) {
        int off = kt * 32;
        #pragma unroll
        for (int pp = 0; pp < 16; ++pp) {
            int kk = wk2 + 2 * pp;
            Ws[kk * 128 + wc] = Wc1[(size_t)(off + kk) * D + wc];
        }
        __syncthreads();
        #pragma unroll 8
        for (int kk = 0; kk < 32; ++kk) {
            float a0 = msgT[(off + kk) * 35 + tr * 2];
            float a1 = msgT[(off + kk) * 35 + tr * 2 + 1];
            float4 w0 = *(const float4*)&Ws[kk * 128 + tc * 4];
            float4 w1 = *(const float4*)&Ws[kk * 128 + 64 + tc * 4];
            float wr[8] = {w0.x, w0.y, w0.z, w0.w, w1.x, w1.y, w1.z, w1.w};
            #pragma unroll
            for (int j = 0; j < 8; ++j) {
                accC[0][j] = fmaf(a0, wr[j], accC[0][j]);
                accC[1][j] = fmaf(a1, wr[j], accC[1][j]);
            }
        }
        __syncthreads();
    }
    // relu -> h1T overwrites msgT (all reads of msgT completed at loop-end sync)
    #pragma unroll
    for (int i = 0; i < 2; ++i) {
        int r = tr * 2 + i;
        #pragma unroll
        for (int j = 0; j < 4; ++j) {
            msgT[(tc * 4 + j) * 35 + r]      = fmaxf(accC[i][j], 0.f);
            msgT[(64 + tc * 4 + j) * 35 + r] = fmaxf(accC[i][j + 4], 0.f);
        }
    }
    __syncthreads();

    // ---------------- Phase C: GEMM2 logits = h1 @ Wc2  [32x128]@[128x60]
    int r2 = tid & 31;
    int cs = tid >> 5;          // 8 col-groups of 8
    float acc2[8];
    #pragma unroll
    for (int j = 0; j < 8; ++j) acc2[j] = 0.f;

    for (int kt = 0; kt < 4; ++kt) {
        int off = kt * 32;
        for (int t = tid; t < 32 * 64; t += 256) {
            int kk = t >> 6, c = t & 63;
            Ws[t] = (c < NCLASS) ? Wc2[(size_t)(off + kk) * NCLASS + c] : 0.f;
        }
        __syncthreads();
        #pragma unroll 4
        for (int kk = 0; kk < 32; ++kk) {
            float h = msgT[(off + kk) * 35 + r2];
            float4 w0 = *(const float4*)&Ws[kk * 64 + cs * 8];
            float4 w1 = *(const float4*)&Ws[kk * 64 + cs * 8 + 4];
            acc2[0] = fmaf(h, w0.x, acc2[0]);
            acc2[1] = fmaf(h, w0.y, acc2[1]);
            acc2[2] = fmaf(h, w0.z, acc2[2]);
            acc2[3] = fmaf(h, w0.w, acc2[3]);
            acc2[4] = fmaf(h, w1.x, acc2[4]);
            acc2[5] = fmaf(h, w1.y, acc2[5]);
            acc2[6] = fmaf(h, w1.z, acc2[6]);
            acc2[7] = fmaf(h, w1.w, acc2[7]);
        }
        __syncthreads();
    }
    {
        int side = r2 >> 4;
        int bb = b0 + (r2 & 15);
        size_t orow = ((size_t)side * BATCH + bb) * NCLASS;
        #pragma unroll
        for (int j = 0; j < 8; ++j) {
            int c = cs * 8 + j;
            if (c < NCLASS) out[orow + c] = acc2[j];
        }
    }
}

// ---------------------------------------------------------------------------
extern "C" void kernel_launch(void* const* d_in, const int* in_sizes, int n_in,
                              void* d_out, int out_size, void* d_ws, size_t ws_size,
                              hipStream_t stream) {
    const float* mem       = (const float*)d_in[0];
    const float* edge_feat = (const float*)d_in[1];
    const float* Wq        = (const float*)d_in[2];
    const float* Wk        = (const float*)d_in[3];
    const float* a         = (const float*)d_in[4];
    const float* Wew       = (const float*)d_in[5];
    const float* Web       = (const float*)d_in[6];
    const float* Wuc       = (const float*)d_in[7];
    const float* Wc1       = (const float*)d_in[8];
    const float* Wc2       = (const float*)d_in[9];
    const int* src_idxs    = (const int*)d_in[10];
    const int* dst_idxs    = (const int*)d_in[11];
    const int* edge_idxs   = (const int*)d_in[12];
    const int* src_nb      = (const int*)d_in[13];
    const int* dst_nb      = (const int*)d_in[14];
    float* out = (float*)d_out;

    float* ws = (float*)d_ws;
    float* Wcomb2 = ws;                  // 384*128
    float* be     = ws + 49152;          // 128
    float* wqa    = ws + 49280;          // 128
    float* wka    = ws + 49408;          // 128

    k_prep<<<50, 256, 0, stream>>>(Wq, Wk, a, Wew, Web, Wuc, wqa, wka, be, Wcomb2);
    k_fused<<<BATCH / NB, 256, 0, stream>>>(mem, edge_feat, Wuc, Wcomb2, be,
                                            wqa, wka, Wc1, Wc2,
                                            src_idxs, dst_idxs, edge_idxs,
                                            src_nb, dst_nb, out);
}

// Round 4
// 495.172 us; speedup vs baseline: 1.1118x; 1.1118x over previous
//
#include <hip/hip_runtime.h>

#define D 128
#define KNBR 32
#define BATCH 8192
#define NCLASS 60
#define NB 16      // b rows per block
#define NP 32      // (b, side) pairs per block

// ---------------------------------------------------------------------------
// K0: prep. blk0: wqa = Wq@a[:D], wka = Wk@a[D:]
//          blk1: be = We_b @ Wuc[384:512]
//          blks 2..49: Wcomb2 = [Wk@Wuc[128:256]; Wk@Wuc[256:384]; We_w@Wuc[384:512]]
__global__ __launch_bounds__(256) void k_prep(
    const float* __restrict__ Wq, const float* __restrict__ Wk,
    const float* __restrict__ a, const float* __restrict__ Wew,
    const float* __restrict__ Web, const float* __restrict__ Wuc,
    float* __restrict__ wqa, float* __restrict__ wka,
    float* __restrict__ be, float* __restrict__ Wcomb2)
{
    __shared__ float sB[128][129];
    int blk = blockIdx.x, tid = threadIdx.x;
    if (blk == 0) {
        for (int t = tid; t < 128 * 128; t += 256) sB[t >> 7][t & 127] = Wq[t];
        __syncthreads();
        if (tid < 128) {
            float s = 0.f;
            for (int j = 0; j < D; ++j) s += sB[tid][j] * a[j];
            wqa[tid] = s;
        }
        __syncthreads();
        for (int t = tid; t < 128 * 128; t += 256) sB[t >> 7][t & 127] = Wk[t];
        __syncthreads();
        if (tid < 128) {
            float s = 0.f;
            for (int j = 0; j < D; ++j) s += sB[tid][j] * a[D + j];
            wka[tid] = s;
        }
    } else if (blk == 1) {
        if (tid < 128) {
            float acc = 0.f;
            for (int j = 0; j < D; ++j) acc += Web[j] * Wuc[(size_t)(384 + j) * D + tid];
            be[tid] = acc;
        }
    } else {
        int g  = (blk - 2) >> 4;
        int rb = ((blk - 2) & 15) * 8;
        const float* A = (g == 2) ? Wew : Wk;
        const float* B = Wuc + (size_t)(128 + g * 128) * D;
        for (int t = tid; t < 128 * 128; t += 256) sB[t >> 7][t & 127] = B[t];
        __syncthreads();
        int j = tid & 127, half = tid >> 7;
        float acc[4] = {0.f, 0.f, 0.f, 0.f};
        int r0 = rb + half * 4;
        for (int t = 0; t < 128; ++t) {
            float bv = sB[t][j];
            #pragma unroll
            for (int m = 0; m < 4; ++m)
                acc[m] = fmaf(A[(size_t)(r0 + m) * D + t], bv, acc[m]);
        }
        #pragma unroll
        for (int m = 0; m < 4; ++m)
            Wcomb2[(size_t)(g * 128 + r0 + m) * D + j] = acc[m];
    }
}

// ---------------------------------------------------------------------------
// K1: per-node scores: sq[n] = mem[n].wqa, sk[n] = mem[n].wka.
// Streams the full node table once, coalesced. 3125 blocks x 64 nodes.
__global__ __launch_bounds__(256) void k_scores(
    const float* __restrict__ mem,
    const float* __restrict__ wqa, const float* __restrict__ wka,
    float* __restrict__ nsq, float* __restrict__ nsk)
{
    int tid = threadIdx.x, lane = tid & 31, grp = tid >> 5;
    int n0 = blockIdx.x * 64 + grp * 8;
    float4 wq4 = ((const float4*)wqa)[lane];
    float4 wk4 = ((const float4*)wka)[lane];
    #pragma unroll
    for (int i = 0; i < 8; ++i) {
        int n = n0 + i;
        float4 v = ((const float4*)(mem + (size_t)n * D))[lane];
        float pq = v.x * wq4.x + v.y * wq4.y + v.z * wq4.z + v.w * wq4.w;
        float pk = v.x * wk4.x + v.y * wk4.y + v.z * wk4.z + v.w * wk4.w;
        #pragma unroll
        for (int m = 1; m <= 16; m <<= 1) {
            pq += __shfl_xor(pq, m, 32);
            pk += __shfl_xor(pk, m, 32);
        }
        if (lane == 0) nsq[n] = pq;
        if (lane == 1) nsk[n] = pk;
    }
}

// ---------------------------------------------------------------------------
// K2: fused attention + msg + cls. 16 b's x 2 sides per block. Single-pass
// neighbor gather (scores precomputed). LDS 50.4 KB -> 3 blocks/CU.
__global__ __launch_bounds__(256, 3) void k_fused(
    const float* __restrict__ mem, const float* __restrict__ edge_feat,
    const float* __restrict__ Wuc, const float* __restrict__ Wcomb2,
    const float* __restrict__ be,
    const float* __restrict__ nsq, const float* __restrict__ nsk,
    const float* __restrict__ Wc1, const float* __restrict__ Wc2,
    const int* __restrict__ src_idxs, const int* __restrict__ dst_idxs,
    const int* __restrict__ edge_idxs,
    const int* __restrict__ src_nb, const int* __restrict__ dst_nb,
    float* __restrict__ out)
{
    __shared__ __align__(16) float Ws[32 * 128];     // 16384 B
    __shared__ __align__(16) float nbT[128 * 33];    // 16896 B  [col][pair]
    __shared__ __align__(16) float uni[128 * 33];    // 16896 B  Ast (32x33) / msgT (128x33)
    __shared__ int s_sidx[NP];
    __shared__ int s_eidx[NB];

    int tid = threadIdx.x;
    int b0 = blockIdx.x * NB;
    int lane = tid & 31;
    int grp  = tid >> 5;

    if (tid < NP) s_sidx[tid] = ((tid >> 4) ? dst_idxs : src_idxs)[b0 + (tid & 15)];
    if (tid < NB) s_eidx[tid] = edge_idxs[b0 + tid];

    // ---------------- Phase A: attention (single gather pass), 8 groups x 4 iters
    for (int it = 0; it < 4; ++it) {
        int p = it * 8 + grp;
        int side = p >> 4;
        int bb = b0 + (p & 15);
        int self_idx = (side ? dst_idxs : src_idxs)[bb];
        int ik = (side ? dst_nb : src_nb)[(size_t)bb * KNBR + lane];

        float x = nsq[self_idx] + nsk[ik];
        x = (x >= 0.f) ? x : 0.2f * x;                  // leaky_relu(0.2)
        float mx = x;
        #pragma unroll
        for (int m = 1; m <= 16; m <<= 1) mx = fmaxf(mx, __shfl_xor(mx, m, 32));
        float e = __expf(x - mx);
        float sum = e;
        #pragma unroll
        for (int m = 1; m <= 16; m <<= 1) sum += __shfl_xor(sum, m, 32);
        float attn = e / sum;

        // weighted neighbor sum: 32 independent row gathers, high MLP
        float4 acc = make_float4(0.f, 0.f, 0.f, 0.f);
        #pragma unroll 8
        for (int k = 0; k < KNBR; ++k) {
            int ikk  = __shfl(ik, k, 32);
            float ak = __shfl(attn, k, 32);
            float4 v = ((const float4*)(mem + (size_t)ikk * D))[lane];
            acc.x = fmaf(ak, v.x, acc.x);
            acc.y = fmaf(ak, v.y, acc.y);
            acc.z = fmaf(ak, v.z, acc.z);
            acc.w = fmaf(ak, v.w, acc.w);
        }
        // store transposed, GEMM-ready: nbT[col][pair]
        nbT[(lane * 4 + 0) * 33 + p] = acc.x;
        nbT[(lane * 4 + 1) * 33 + p] = acc.y;
        nbT[(lane * 4 + 2) * 33 + p] = acc.z;
        nbT[(lane * 4 + 3) * 33 + p] = acc.w;
    }
    __syncthreads();

    // ---------------- Phase B: msg = relu(A @ [Wuc; Wcomb2] + be), A = [32 x 512]
    int tr = tid >> 4, tc = tid & 15;          // 16x16 micro grid, 2 rows x 8 cols
    int lc = tid & 31, lr = tid >> 5;          // A staging lanes
    int wc = tid & 127, wk2 = tid >> 7;        // W staging lanes
    float accB[2][8];
    #pragma unroll
    for (int i = 0; i < 2; ++i)
        #pragma unroll
        for (int j = 0; j < 8; ++j) accB[i][j] = 0.f;

    float* Ast = uni;

    // seg 0 (kt 0..3): A = self rows, staged from mem
    for (int kt = 0; kt < 4; ++kt) {
        int off = kt * 32;
        #pragma unroll
        for (int q = 0; q < 4; ++q) {
            int r = lr + 8 * q;
            Ast[lc * 33 + r] = mem[(size_t)s_sidx[r] * D + off + lc];
        }
        #pragma unroll
        for (int pp = 0; pp < 16; ++pp) {
            int kk = wk2 + 2 * pp;
            Ws[kk * 128 + wc] = Wuc[(size_t)(off + kk) * D + wc];
        }
        __syncthreads();
        #pragma unroll 8
        for (int kk = 0; kk < 32; ++kk) {
            float a0 = Ast[kk * 33 + tr * 2];
            float a1 = Ast[kk * 33 + tr * 2 + 1];
            float4 w0 = *(const float4*)&Ws[kk * 128 + tc * 4];
            float4 w1 = *(const float4*)&Ws[kk * 128 + 64 + tc * 4];
            float wr[8] = {w0.x, w0.y, w0.z, w0.w, w1.x, w1.y, w1.z, w1.w};
            #pragma unroll
            for (int j = 0; j < 8; ++j) {
                accB[0][j] = fmaf(a0, wr[j], accB[0][j]);
                accB[1][j] = fmaf(a1, wr[j], accB[1][j]);
            }
        }
        __syncthreads();
    }
    // segs 1-2 (kt 4..11): A read directly from nbT (no staging)
    for (int kt = 4; kt < 12; ++kt) {
        int off = (kt & 3) * 32;
        int gr0 = kt * 32 - 128;
        #pragma unroll
        for (int pp = 0; pp < 16; ++pp) {
            int kk = wk2 + 2 * pp;
            Ws[kk * 128 + wc] = Wcomb2[(size_t)(gr0 + kk) * D + wc];
        }
        __syncthreads();
        int r0 = (kt < 8) ? (tr * 2) : ((tr * 2) ^ 16);
        #pragma unroll 8
        for (int kk = 0; kk < 32; ++kk) {
            float a0 = nbT[(off + kk) * 33 + r0];
            float a1 = nbT[(off + kk) * 33 + r0 + 1];
            float4 w0 = *(const float4*)&Ws[kk * 128 + tc * 4];
            float4 w1 = *(const float4*)&Ws[kk * 128 + 64 + tc * 4];
            float wr[8] = {w0.x, w0.y, w0.z, w0.w, w1.x, w1.y, w1.z, w1.w};
            #pragma unroll
            for (int j = 0; j < 8; ++j) {
                accB[0][j] = fmaf(a0, wr[j], accB[0][j]);
                accB[1][j] = fmaf(a1, wr[j], accB[1][j]);
            }
        }
        __syncthreads();
    }
    // seg 3 (kt 12..15): A = edge rows, staged from edge_feat
    for (int kt = 12; kt < 16; ++kt) {
        int off = (kt & 3) * 32;
        int gr0 = kt * 32 - 128;
        #pragma unroll
        for (int q = 0; q < 4; ++q) {
            int r = lr + 8 * q;
            Ast[lc * 33 + r] = edge_feat[(size_t)s_eidx[r & 15] * D + off + lc];
        }
        #pragma unroll
        for (int pp = 0; pp < 16; ++pp) {
            int kk = wk2 + 2 * pp;
            Ws[kk * 128 + wc] = Wcomb2[(size_t)(gr0 + kk) * D + wc];
        }
        __syncthreads();
        #pragma unroll 8
        for (int kk = 0; kk < 32; ++kk) {
            float a0 = Ast[kk * 33 + tr * 2];
            float a1 = Ast[kk * 33 + tr * 2 + 1];
            float4 w0 = *(const float4*)&Ws[kk * 128 + tc * 4];
            float4 w1 = *(const float4*)&Ws[kk * 128 + 64 + tc * 4];
            float wr[8] = {w0.x, w0.y, w0.z, w0.w, w1.x, w1.y, w1.z, w1.w};
            #pragma unroll
            for (int j = 0; j < 8; ++j) {
                accB[0][j] = fmaf(a0, wr[j], accB[0][j]);
                accB[1][j] = fmaf(a1, wr[j], accB[1][j]);
            }
        }
        __syncthreads();
    }

    // bias + relu -> msgT[col][row]  (uni: Ast is dead, last read was pre-sync)
    float* msgT = uni;
    {
        float4 bv0 = *(const float4*)&be[tc * 4];
        float4 bv1 = *(const float4*)&be[64 + tc * 4];
        float b8[8] = {bv0.x, bv0.y, bv0.z, bv0.w, bv1.x, bv1.y, bv1.z, bv1.w};
        #pragma unroll
        for (int i = 0; i < 2; ++i) {
            int r = tr * 2 + i;
            #pragma unroll
            for (int j = 0; j < 4; ++j) {
                msgT[(tc * 4 + j) * 33 + r]      = fmaxf(accB[i][j] + b8[j], 0.f);
                msgT[(64 + tc * 4 + j) * 33 + r] = fmaxf(accB[i][j + 4] + b8[j + 4], 0.f);
            }
        }
    }
    __syncthreads();

    // ---------------- Phase C: GEMM1 h1 = relu(msg @ Wc1)
    float accC[2][8];
    #pragma unroll
    for (int i = 0; i < 2; ++i)
        #pragma unroll
        for (int j = 0; j < 8; ++j) accC[i][j] = 0.f;

    for (int kt = 0; kt < 4; ++kt) {
        int off = kt * 32;
        #pragma unroll
        for (int pp = 0; pp < 16; ++pp) {
            int kk = wk2 + 2 * pp;
            Ws[kk * 128 + wc] = Wc1[(size_t)(off + kk) * D + wc];
        }
        __syncthreads();
        #pragma unroll 8
        for (int kk = 0; kk < 32; ++kk) {
            float a0 = msgT[(off + kk) * 33 + tr * 2];
            float a1 = msgT[(off + kk) * 33 + tr * 2 + 1];
            float4 w0 = *(const float4*)&Ws[kk * 128 + tc * 4];
            float4 w1 = *(const float4*)&Ws[kk * 128 + 64 + tc * 4];
            float wr[8] = {w0.x, w0.y, w0.z, w0.w, w1.x, w1.y, w1.z, w1.w};
            #pragma unroll
            for (int j = 0; j < 8; ++j) {
                accC[0][j] = fmaf(a0, wr[j], accC[0][j]);
                accC[1][j] = fmaf(a1, wr[j], accC[1][j]);
            }
        }
        __syncthreads();
    }
    // relu -> h1T overwrites msgT
    #pragma unroll
    for (int i = 0; i < 2; ++i) {
        int r = tr * 2 + i;
        #pragma unroll
        for (int j = 0; j < 4; ++j) {
            msgT[(tc * 4 + j) * 33 + r]      = fmaxf(accC[i][j], 0.f);
            msgT[(64 + tc * 4 + j) * 33 + r] = fmaxf(accC[i][j + 4], 0.f);
        }
    }
    __syncthreads();

    // ---------------- Phase C: GEMM2 logits = h1 @ Wc2  [32x128]@[128x60]
    int r2 = tid & 31;
    int cs = tid >> 5;
    float acc2[8];
    #pragma unroll
    for (int j = 0; j < 8; ++j) acc2[j] = 0.f;

    for (int kt = 0; kt < 4; ++kt) {
        int off = kt * 32;
        for (int t = tid; t < 32 * 64; t += 256) {
            int kk = t >> 6, c = t & 63;
            Ws[t] = (c < NCLASS) ? Wc2[(size_t)(off + kk) * NCLASS + c] : 0.f;
        }
        __syncthreads();
        #pragma unroll 4
        for (int kk = 0; kk < 32; ++kk) {
            float h = msgT[(off + kk) * 33 + r2];
            float4 w0 = *(const float4*)&Ws[kk * 64 + cs * 8];
            float4 w1 = *(const float4*)&Ws[kk * 64 + cs * 8 + 4];
            acc2[0] = fmaf(h, w0.x, acc2[0]);
            acc2[1] = fmaf(h, w0.y, acc2[1]);
            acc2[2] = fmaf(h, w0.z, acc2[2]);
            acc2[3] = fmaf(h, w0.w, acc2[3]);
            acc2[4] = fmaf(h, w1.x, acc2[4]);
            acc2[5] = fmaf(h, w1.y, acc2[5]);
            acc2[6] = fmaf(h, w1.z, acc2[6]);
            acc2[7] = fmaf(h, w1.w, acc2[7]);
        }
        __syncthreads();
    }
    {
        int side = r2 >> 4;
        int bb = b0 + (r2 & 15);
        size_t orow = ((size_t)side * BATCH + bb) * NCLASS;
        #pragma unroll
        for (int j = 0; j < 8; ++j) {
            int c = cs * 8 + j;
            if (c < NCLASS) out[orow + c] = acc2[j];
        }
    }
}

// ---------------------------------------------------------------------------
extern "C" void kernel_launch(void* const* d_in, const int* in_sizes, int n_in,
                              void* d_out, int out_size, void* d_ws, size_t ws_size,
                              hipStream_t stream) {
    const float* mem       = (const float*)d_in[0];
    const float* edge_feat = (const float*)d_in[1];
    const float* Wq        = (const float*)d_in[2];
    const float* Wk        = (const float*)d_in[3];
    const float* a         = (const float*)d_in[4];
    const float* Wew       = (const float*)d_in[5];
    const float* Web       = (const float*)d_in[6];
    const float* Wuc       = (const float*)d_in[7];
    const float* Wc1       = (const float*)d_in[8];
    const float* Wc2       = (const float*)d_in[9];
    const int* src_idxs    = (const int*)d_in[10];
    const int* dst_idxs    = (const int*)d_in[11];
    const int* edge_idxs   = (const int*)d_in[12];
    const int* src_nb      = (const int*)d_in[13];
    const int* dst_nb      = (const int*)d_in[14];
    float* out = (float*)d_out;

    float* ws = (float*)d_ws;
    float* Wcomb2 = ws;                  // 384*128 = 49152
    float* be     = ws + 49152;          // 128
    float* wqa    = ws + 49280;          // 128
    float* wka    = ws + 49408;          // 128
    float* nsq    = ws + 49536;          // 200000
    float* nsk    = ws + 249536;         // 200000

    k_prep<<<50, 256, 0, stream>>>(Wq, Wk, a, Wew, Web, Wuc, wqa, wka, be, Wcomb2);
    k_scores<<<200000 / 64, 256, 0, stream>>>(mem, wqa, wka, nsq, nsk);
    k_fused<<<BATCH / NB, 256, 0, stream>>>(mem, edge_feat, Wuc, Wcomb2, be,
                                            nsq, nsk, Wc1, Wc2,
                                            src_idxs, dst_idxs, edge_idxs,
                                            src_nb, dst_nb, out);
}